// Round 4
// baseline (196.954 us; speedup 1.0000x reference)
//
#include <hip/hip_runtime.h>
#include <hip/hip_bf16.h>
#include <cstddef>

#define NBATCH 16384
#define NNB 32
#define DD 128
#define NH 4
#define NHD 512   // NH * DD
#define BB 16     // batches per block
#define NT 512    // threads per block

// ---------------------------------------------------------------------------
// K0: precompute A_all[i][h*128+d] = sum_r Wq[h][r][i] * Wk[h][r][d]
//     and       C_all[h*128+i][o]  = 0.25 * sum_d Wo[o][d] * Wv[h][d][i]
// ---------------------------------------------------------------------------
__global__ __launch_bounds__(256) void precompute_kernel(
    const float* __restrict__ Wq, const float* __restrict__ Wk,
    const float* __restrict__ Wv, const float* __restrict__ Wo,
    float* __restrict__ AA, float* __restrict__ CC) {
  int e = blockIdx.x * 256 + threadIdx.x;   // 0..65535
  if (blockIdx.y == 0) {
    int i = e >> 9;            // 0..127
    int hd = e & 511;
    int h = hd >> 7, d = hd & 127;
    const float* wq = Wq + h * 16384;
    const float* wk = Wk + h * 16384;
    float acc = 0.f;
    #pragma unroll 8
    for (int r = 0; r < 128; ++r) acc += wq[r * 128 + i] * wk[r * 128 + d];
    AA[e] = acc;
  } else {
    int hi = e >> 7;           // 0..511
    int o = e & 127;
    int h = hi >> 7, i = hi & 127;
    const float* wv = Wv + h * 16384;
    float acc = 0.f;
    #pragma unroll 8
    for (int d = 0; d < 128; ++d) acc += Wo[o * 128 + d] * wv[d * 128 + i];
    CC[e] = 0.25f * acc;
  }
}

// ---------------------------------------------------------------------------
// Fused: gemm1 (g = x@AA) -> attention (logits/softmax/weighted-sum, nb read
// ONCE into registers, column-major per lane, butterfly reduction) ->
// gemm2 (out = ws@CC + bo, leaky). Block = 512 thr, 16 batches, 80 KB LDS.
// LDS caps residency at 2 blocks/CU = 4 waves/EU, so pin waves_per_eu=(4,4)
// to get the full 128-VGPR budget (R3: compiler chose 64 VGPR -> v[64]
// spilled -> 196 MB scratch write traffic).
// ---------------------------------------------------------------------------
__global__ __attribute__((amdgpu_flat_work_group_size(NT, NT),
                          amdgpu_waves_per_eu(4, 4)))
void fused_kernel(
    const float* __restrict__ x, const float* __restrict__ nb,
    const float* __restrict__ AA, const float* __restrict__ CC,
    const float* __restrict__ bo, float* __restrict__ out) {

  __shared__ __align__(16) float x_lds[BB][DD];        // 8 KB
  __shared__ __align__(16) float g_lds[BB][NHD];       // 32 KB (reused as partials)
  __shared__ __align__(16) float ws_lds[BB][NHD];      // 32 KB
  __shared__ __align__(16) float attn_lds[BB][NNB*NH]; // 8 KB

  const int t = threadIdx.x;
  const int b0 = blockIdx.x * BB;

  // ---- phase 0: stage x rows (16 x 128 = 512 float4, one per thread)
  {
    float4 v = ((const float4*)(x + (size_t)b0 * DD))[t];
    ((float4*)x_lds)[t] = v;
  }
  __syncthreads();

  // ---- phase 1: g[b][hd] = sum_i x[b][i] * AA[i][hd]
  {
    const int hdq = t & 127;   // hd = 4*hdq
    const int bq  = t >> 7;    // batches 4*bq .. 4*bq+3
    const float4* AA4 = (const float4*)AA;   // [128][128] float4
    float4 acc[4];
    #pragma unroll
    for (int j = 0; j < 4; ++j) acc[j] = make_float4(0.f, 0.f, 0.f, 0.f);
    #pragma unroll 2
    for (int i4 = 0; i4 < 128; i4 += 4) {
      float4 a0 = AA4[(i4 + 0) * 128 + hdq];
      float4 a1 = AA4[(i4 + 1) * 128 + hdq];
      float4 a2 = AA4[(i4 + 2) * 128 + hdq];
      float4 a3 = AA4[(i4 + 3) * 128 + hdq];
      #pragma unroll
      for (int j = 0; j < 4; ++j) {
        float4 xv = *(const float4*)&x_lds[4 * bq + j][i4];  // wave-uniform b128
        acc[j].x += xv.x * a0.x + xv.y * a1.x + xv.z * a2.x + xv.w * a3.x;
        acc[j].y += xv.x * a0.y + xv.y * a1.y + xv.z * a2.y + xv.w * a3.y;
        acc[j].z += xv.x * a0.z + xv.y * a1.z + xv.z * a2.z + xv.w * a3.z;
        acc[j].w += xv.x * a0.w + xv.y * a1.w + xv.z * a2.w + xv.w * a3.w;
      }
    }
    #pragma unroll
    for (int j = 0; j < 4; ++j)
      *(float4*)&g_lds[4 * bq + j][4 * hdq] = acc[j];
  }
  __syncthreads();

  // ---- phase 2: attention; wave owns 2 batches, nb in registers col-major
  {
    const int wv_ = t >> 6;      // wave 0..7
    const int lane = t & 63;
    // after the 5-step butterfly, lane holds n = bit-reversal(lane bits 0..4)
    const int nl = ((lane & 1) << 4) | ((lane & 2) << 2) | (lane & 4) |
                   ((lane & 8) >> 2) | ((lane & 16) >> 4);
    const int bit0 = lane & 1;
    #pragma unroll 1
    for (int c = 0; c < 2; ++c) {
      const int b = 2 * wv_ + c;
      const float* nbb = nb + ((size_t)(b0 + b)) * (NNB * DD);
      float v[64];   // lane owns columns 2*lane, 2*lane+1 for all 32 rows
      #pragma unroll
      for (int n = 0; n < 32; ++n) {
        float2 f = *(const float2*)(nbb + n * DD + 2 * lane);
        v[2 * n] = f.x; v[2 * n + 1] = f.y;
      }
      #pragma unroll
      for (int h = 0; h < NH; ++h) {
        float2 g2 = *(const float2*)&g_lds[b][h * DD + 2 * lane];
        // generate partials and fold in butterfly step 0 immediately (p: 16 regs)
        float p[16];
        #pragma unroll
        for (int k = 0; k < 16; ++k) {
          float plo = g2.x * v[2 * k]        + g2.y * v[2 * k + 1];
          float phi = g2.x * v[2 * (k + 16)] + g2.y * v[2 * (k + 16) + 1];
          float keep = bit0 ? phi : plo;
          float send = bit0 ? plo : phi;
          p[k] = keep + __shfl_xor(send, 1);
        }
        // butterfly steps 1..4: exchange the NOT-kept half, add to kept half
        #pragma unroll
        for (int s = 1; s < 5; ++s) {
          const int nsel = 16 >> s;
          const int bit = (lane >> s) & 1;
          #pragma unroll
          for (int k = 0; k < nsel; ++k) {
            float keep = bit ? p[k + nsel] : p[k];
            float send = bit ? p[k] : p[k + nsel];
            p[k] = keep + __shfl_xor(send, 1 << s);
          }
        }
        float tot = p[0] + __shfl_xor(p[0], 32);  // full 128-col logit for n=nl
        // tot is identical in lanes l and l^32 -> reduce only within 32 lanes
        float m = tot;
        #pragma unroll
        for (int off = 16; off >= 1; off >>= 1)
          m = fmaxf(m, __shfl_xor(m, off));
        float e = __expf(tot - m);
        float s64 = e;
        #pragma unroll
        for (int off = 16; off >= 1; off >>= 1)
          s64 += __shfl_xor(s64, off);
        float attnv = e / s64;            // sum over the 32 distinct n's
        attn_lds[b][nl * 4 + h] = attnv;  // duplicate write (same value) benign
      }
      // weighted neighbor sum from the SAME registers (no nb re-read)
      float wsa[NH][2];
      #pragma unroll
      for (int h = 0; h < NH; ++h) { wsa[h][0] = 0.f; wsa[h][1] = 0.f; }
      #pragma unroll
      for (int n = 0; n < 32; ++n) {
        float4 a4 = *(const float4*)&attn_lds[b][n * 4];  // uniform broadcast
        wsa[0][0] += a4.x * v[2 * n]; wsa[0][1] += a4.x * v[2 * n + 1];
        wsa[1][0] += a4.y * v[2 * n]; wsa[1][1] += a4.y * v[2 * n + 1];
        wsa[2][0] += a4.z * v[2 * n]; wsa[2][1] += a4.z * v[2 * n + 1];
        wsa[3][0] += a4.w * v[2 * n]; wsa[3][1] += a4.w * v[2 * n + 1];
      }
      #pragma unroll
      for (int h = 0; h < NH; ++h)
        *(float2*)&ws_lds[b][h * DD + 2 * lane] = make_float2(wsa[h][0], wsa[h][1]);
    }
  }
  __syncthreads();

  // ---- phase 3: gemm2 partials, k split across 4 thread groups
  {
    const int oq = t & 31;         // o = 4*oq
    const int bq = (t >> 5) & 3;   // batches 4*bq .. 4*bq+3
    const int kg = t >> 7;         // k range kg*128 .. +127
    const float4* CC4 = (const float4*)CC;   // [512][32] float4
    float4 acc[4];
    #pragma unroll
    for (int j = 0; j < 4; ++j) acc[j] = make_float4(0.f, 0.f, 0.f, 0.f);
    const int kbase = kg * 128;
    #pragma unroll 2
    for (int kk = 0; kk < 128; kk += 4) {
      const int k = kbase + kk;
      float4 c0 = CC4[(k + 0) * 32 + oq];
      float4 c1 = CC4[(k + 1) * 32 + oq];
      float4 c2 = CC4[(k + 2) * 32 + oq];
      float4 c3 = CC4[(k + 3) * 32 + oq];
      #pragma unroll
      for (int j = 0; j < 4; ++j) {
        float4 w = *(const float4*)&ws_lds[4 * bq + j][k];  // 2-addr broadcast
        acc[j].x += w.x * c0.x + w.y * c1.x + w.z * c2.x + w.w * c3.x;
        acc[j].y += w.x * c0.y + w.y * c1.y + w.z * c2.y + w.w * c3.y;
        acc[j].z += w.x * c0.z + w.y * c1.z + w.z * c2.z + w.w * c3.z;
        acc[j].w += w.x * c0.w + w.y * c1.w + w.z * c2.w + w.w * c3.w;
      }
    }
    // partials into g_lds (dead after phase 2): [4 kg][16 b][128 o] = 32 KB
    float* part = (float*)g_lds;
    #pragma unroll
    for (int j = 0; j < 4; ++j)
      *(float4*)&part[((kg * BB) + (4 * bq + j)) * DD + 4 * oq] = acc[j];
  }
  __syncthreads();

  // ---- phase 4: reduce partials + bias + leaky relu + store
  {
    const int o4 = t & 31;
    const int b  = t >> 5;   // 0..15
    const float* part = (const float*)g_lds;
    float4 p0 = *(const float4*)&part[(0 * BB + b) * DD + 4 * o4];
    float4 p1 = *(const float4*)&part[(1 * BB + b) * DD + 4 * o4];
    float4 p2 = *(const float4*)&part[(2 * BB + b) * DD + 4 * o4];
    float4 p3 = *(const float4*)&part[(3 * BB + b) * DD + 4 * o4];
    float4 bias = ((const float4*)bo)[o4];
    float r0 = p0.x + p1.x + p2.x + p3.x + bias.x;
    float r1 = p0.y + p1.y + p2.y + p3.y + bias.y;
    float r2 = p0.z + p1.z + p2.z + p3.z + bias.z;
    float r3 = p0.w + p1.w + p2.w + p3.w + bias.w;
    float4 r;
    r.x = r0 > 0.f ? r0 : 0.01f * r0;
    r.y = r1 > 0.f ? r1 : 0.01f * r1;
    r.z = r2 > 0.f ? r2 : 0.01f * r2;
    r.w = r3 > 0.f ? r3 : 0.01f * r3;
    ((float4*)(out + (size_t)(b0 + b) * DD))[o4] = r;
  }
}

// ---------------------------------------------------------------------------
extern "C" void kernel_launch(void* const* d_in, const int* in_sizes, int n_in,
                              void* d_out, int out_size, void* d_ws, size_t ws_size,
                              hipStream_t stream) {
  const float* x  = (const float*)d_in[0];
  const float* nb = (const float*)d_in[1];
  const float* Wq = (const float*)d_in[2];
  const float* Wk = (const float*)d_in[3];
  const float* Wv = (const float*)d_in[4];
  const float* Wo = (const float*)d_in[5];
  const float* bo = (const float*)d_in[6];
  float* out = (float*)d_out;

  float* ws = (float*)d_ws;
  float* AA = ws;            // [128][512]
  float* CC = ws + 65536;    // [512][128]

  precompute_kernel<<<dim3(256, 2), 256, 0, stream>>>(Wq, Wk, Wv, Wo, AA, CC);
  fused_kernel<<<dim3(NBATCH / BB), NT, 0, stream>>>(x, nb, AA, CC, bo, out);
}

// Round 5
// 151.384 us; speedup vs baseline: 1.3010x; 1.3010x over previous
//
#include <hip/hip_runtime.h>
#include <hip/hip_bf16.h>
#include <cstddef>

#define NBATCH 16384
#define NNB 32
#define DD 128
#define NH 4
#define NHD 512   // NH * DD
#define BB 16     // batches per block
#define NT 512    // threads per block

// ---------------------------------------------------------------------------
// K0: precompute A_all[i][h*128+d] = sum_r Wq[h][r][i] * Wk[h][r][d]
//     and       C_all[h*128+i][o]  = 0.25 * sum_d Wo[o][d] * Wv[h][d][i]
// ---------------------------------------------------------------------------
__global__ __launch_bounds__(256) void precompute_kernel(
    const float* __restrict__ Wq, const float* __restrict__ Wk,
    const float* __restrict__ Wv, const float* __restrict__ Wo,
    float* __restrict__ AA, float* __restrict__ CC) {
  int e = blockIdx.x * 256 + threadIdx.x;   // 0..65535
  if (blockIdx.y == 0) {
    int i = e >> 9;            // 0..127
    int hd = e & 511;
    int h = hd >> 7, d = hd & 127;
    const float* wq = Wq + h * 16384;
    const float* wk = Wk + h * 16384;
    float acc = 0.f;
    #pragma unroll 8
    for (int r = 0; r < 128; ++r) acc += wq[r * 128 + i] * wk[r * 128 + d];
    AA[e] = acc;
  } else {
    int hi = e >> 7;           // 0..511
    int o = e & 127;
    int h = hi >> 7, i = hi & 127;
    const float* wv = Wv + h * 16384;
    float acc = 0.f;
    #pragma unroll 8
    for (int d = 0; d < 128; ++d) acc += Wo[o * 128 + d] * wv[d * 128 + i];
    CC[e] = 0.25f * acc;
  }
}

// ---------------------------------------------------------------------------
// Fused kernel. Phase 2 redesigned (R4 -> R5): STREAMING two-pass attention,
// peak live regs ~35 (R3/R4 held nb tile in v[64] -> compiler gave 64 VGPR ->
// ~190 MB scratch spill traffic, 225 us). Pass A: logits (nb streamed, g from
// LDS broadcast). Pass B: weighted sum (nb re-streamed, L1/L2-hot).
// ---------------------------------------------------------------------------
__global__ __launch_bounds__(NT, 4) void fused_kernel(
    const float* __restrict__ x, const float* __restrict__ nb,
    const float* __restrict__ AA, const float* __restrict__ CC,
    const float* __restrict__ bo, float* __restrict__ out) {

  __shared__ __align__(16) float x_lds[BB][DD];        // 8 KB
  __shared__ __align__(16) float g_lds[BB][NHD];       // 32 KB (reused as partials)
  __shared__ __align__(16) float ws_lds[BB][NHD];      // 32 KB
  __shared__ __align__(16) float attn_lds[BB][NNB*NH]; // 8 KB

  const int t = threadIdx.x;
  const int b0 = blockIdx.x * BB;

  // ---- phase 0: stage x rows (16 x 128 = 512 float4, one per thread)
  {
    float4 v = ((const float4*)(x + (size_t)b0 * DD))[t];
    ((float4*)x_lds)[t] = v;
  }
  __syncthreads();

  // ---- phase 1: g[b][hd] = sum_i x[b][i] * AA[i][hd]
  {
    const int hdq = t & 127;   // hd = 4*hdq
    const int bq  = t >> 7;    // batches 4*bq .. 4*bq+3
    const float4* AA4 = (const float4*)AA;   // [128][128] float4
    float4 acc[4];
    #pragma unroll
    for (int j = 0; j < 4; ++j) acc[j] = make_float4(0.f, 0.f, 0.f, 0.f);
    #pragma unroll 2
    for (int i4 = 0; i4 < 128; i4 += 4) {
      float4 a0 = AA4[(i4 + 0) * 128 + hdq];
      float4 a1 = AA4[(i4 + 1) * 128 + hdq];
      float4 a2 = AA4[(i4 + 2) * 128 + hdq];
      float4 a3 = AA4[(i4 + 3) * 128 + hdq];
      #pragma unroll
      for (int j = 0; j < 4; ++j) {
        float4 xv = *(const float4*)&x_lds[4 * bq + j][i4];  // wave-uniform b128
        acc[j].x += xv.x * a0.x + xv.y * a1.x + xv.z * a2.x + xv.w * a3.x;
        acc[j].y += xv.x * a0.y + xv.y * a1.y + xv.z * a2.y + xv.w * a3.y;
        acc[j].z += xv.x * a0.z + xv.y * a1.z + xv.z * a2.z + xv.w * a3.z;
        acc[j].w += xv.x * a0.w + xv.y * a1.w + xv.z * a2.w + xv.w * a3.w;
      }
    }
    #pragma unroll
    for (int j = 0; j < 4; ++j)
      *(float4*)&g_lds[4 * bq + j][4 * hdq] = acc[j];
  }
  __syncthreads();

  // ---- phase 2: attention, streaming two-pass; wave owns 2 batches
  {
    const int wv_ = t >> 6;        // wave 0..7
    const int lane = t & 63;
    const int n = lane & 31, half = lane >> 5;
    #pragma unroll 1
    for (int c = 0; c < 2; ++c) {
      const int b = 2 * wv_ + c;
      // ---- pass A: logits. lane reads neighbor n's half-row, streaming.
      const float* nrow = nb + ((size_t)(b0 + b) * NNB + n) * DD + half * 64;
      float acc0 = 0.f, acc1 = 0.f, acc2 = 0.f, acc3 = 0.f;
      #pragma unroll
      for (int j = 0; j < 16; ++j) {
        float4 f = ((const float4*)nrow)[j];
        float4 g0 = *(const float4*)&g_lds[b][0 * DD + half * 64 + 4 * j];
        float4 g1 = *(const float4*)&g_lds[b][1 * DD + half * 64 + 4 * j];
        float4 g2 = *(const float4*)&g_lds[b][2 * DD + half * 64 + 4 * j];
        float4 g3 = *(const float4*)&g_lds[b][3 * DD + half * 64 + 4 * j];
        acc0 += f.x * g0.x + f.y * g0.y + f.z * g0.z + f.w * g0.w;
        acc1 += f.x * g1.x + f.y * g1.y + f.z * g1.z + f.w * g1.w;
        acc2 += f.x * g2.x + f.y * g2.y + f.z * g2.z + f.w * g2.w;
        acc3 += f.x * g3.x + f.y * g3.y + f.z * g3.z + f.w * g3.w;
      }
      // combine halves: lanes (n, n+32) both get the full logit
      float lg0 = acc0 + __shfl_xor(acc0, 32);
      float lg1 = acc1 + __shfl_xor(acc1, 32);
      float lg2 = acc2 + __shfl_xor(acc2, 32);
      float lg3 = acc3 + __shfl_xor(acc3, 32);
      // softmax over the 32 n's (each 32-lane half holds all 32 n's)
      float4 aw;
      {
        float m0 = lg0, m1 = lg1, m2 = lg2, m3 = lg3;
        #pragma unroll
        for (int off = 16; off >= 1; off >>= 1) {
          m0 = fmaxf(m0, __shfl_xor(m0, off));
          m1 = fmaxf(m1, __shfl_xor(m1, off));
          m2 = fmaxf(m2, __shfl_xor(m2, off));
          m3 = fmaxf(m3, __shfl_xor(m3, off));
        }
        float e0 = __expf(lg0 - m0), e1 = __expf(lg1 - m1);
        float e2 = __expf(lg2 - m2), e3 = __expf(lg3 - m3);
        float s0 = e0, s1 = e1, s2 = e2, s3 = e3;
        #pragma unroll
        for (int off = 16; off >= 1; off >>= 1) {
          s0 += __shfl_xor(s0, off);
          s1 += __shfl_xor(s1, off);
          s2 += __shfl_xor(s2, off);
          s3 += __shfl_xor(s3, off);
        }
        aw = make_float4(e0 / s0, e1 / s1, e2 / s2, e3 / s3);
      }
      if (half == 0) *(float4*)&attn_lds[b][n * 4] = aw;
      // ---- pass B: weighted sum. lane owns columns (2*lane, 2*lane+1).
      // nb tile re-streamed; reuse distance ~50 instrs -> L1/L2-hot.
      float w00 = 0.f, w01 = 0.f, w10 = 0.f, w11 = 0.f;
      float w20 = 0.f, w21 = 0.f, w30 = 0.f, w31 = 0.f;
      const float* nbb = nb + (size_t)(b0 + b) * (NNB * DD);
      #pragma unroll 8
      for (int n2 = 0; n2 < NNB; ++n2) {
        float2 f2 = *(const float2*)(nbb + n2 * DD + 2 * lane);
        float4 a4 = *(const float4*)&attn_lds[b][n2 * 4];  // uniform broadcast
        w00 += a4.x * f2.x; w01 += a4.x * f2.y;
        w10 += a4.y * f2.x; w11 += a4.y * f2.y;
        w20 += a4.z * f2.x; w21 += a4.z * f2.y;
        w30 += a4.w * f2.x; w31 += a4.w * f2.y;
      }
      *(float2*)&ws_lds[b][0 * DD + 2 * lane] = make_float2(w00, w01);
      *(float2*)&ws_lds[b][1 * DD + 2 * lane] = make_float2(w10, w11);
      *(float2*)&ws_lds[b][2 * DD + 2 * lane] = make_float2(w20, w21);
      *(float2*)&ws_lds[b][3 * DD + 2 * lane] = make_float2(w30, w31);
    }
  }
  __syncthreads();

  // ---- phase 3: gemm2 partials, k split across 4 thread groups
  {
    const int oq = t & 31;         // o = 4*oq
    const int bq = (t >> 5) & 3;   // batches 4*bq .. 4*bq+3
    const int kg = t >> 7;         // k range kg*128 .. +127
    const float4* CC4 = (const float4*)CC;   // [512][32] float4
    float4 acc[4];
    #pragma unroll
    for (int j = 0; j < 4; ++j) acc[j] = make_float4(0.f, 0.f, 0.f, 0.f);
    const int kbase = kg * 128;
    #pragma unroll 2
    for (int kk = 0; kk < 128; kk += 4) {
      const int k = kbase + kk;
      float4 c0 = CC4[(k + 0) * 32 + oq];
      float4 c1 = CC4[(k + 1) * 32 + oq];
      float4 c2 = CC4[(k + 2) * 32 + oq];
      float4 c3 = CC4[(k + 3) * 32 + oq];
      #pragma unroll
      for (int j = 0; j < 4; ++j) {
        float4 w = *(const float4*)&ws_lds[4 * bq + j][k];  // 2-addr broadcast
        acc[j].x += w.x * c0.x + w.y * c1.x + w.z * c2.x + w.w * c3.x;
        acc[j].y += w.x * c0.y + w.y * c1.y + w.z * c2.y + w.w * c3.y;
        acc[j].z += w.x * c0.z + w.y * c1.z + w.z * c2.z + w.w * c3.z;
        acc[j].w += w.x * c0.w + w.y * c1.w + w.z * c2.w + w.w * c3.w;
      }
    }
    // partials into g_lds (dead after phase 2): [4 kg][16 b][128 o] = 32 KB
    float* part = (float*)g_lds;
    #pragma unroll
    for (int j = 0; j < 4; ++j)
      *(float4*)&part[((kg * BB) + (4 * bq + j)) * DD + 4 * oq] = acc[j];
  }
  __syncthreads();

  // ---- phase 4: reduce partials + bias + leaky relu + store
  {
    const int o4 = t & 31;
    const int b  = t >> 5;   // 0..15
    const float* part = (const float*)g_lds;
    float4 p0 = *(const float4*)&part[(0 * BB + b) * DD + 4 * o4];
    float4 p1 = *(const float4*)&part[(1 * BB + b) * DD + 4 * o4];
    float4 p2 = *(const float4*)&part[(2 * BB + b) * DD + 4 * o4];
    float4 p3 = *(const float4*)&part[(3 * BB + b) * DD + 4 * o4];
    float4 bias = ((const float4*)bo)[o4];
    float r0 = p0.x + p1.x + p2.x + p3.x + bias.x;
    float r1 = p0.y + p1.y + p2.y + p3.y + bias.y;
    float r2 = p0.z + p1.z + p2.z + p3.z + bias.z;
    float r3 = p0.w + p1.w + p2.w + p3.w + bias.w;
    float4 r;
    r.x = r0 > 0.f ? r0 : 0.01f * r0;
    r.y = r1 > 0.f ? r1 : 0.01f * r1;
    r.z = r2 > 0.f ? r2 : 0.01f * r2;
    r.w = r3 > 0.f ? r3 : 0.01f * r3;
    ((float4*)(out + (size_t)(b0 + b) * DD))[o4] = r;
  }
}

// ---------------------------------------------------------------------------
extern "C" void kernel_launch(void* const* d_in, const int* in_sizes, int n_in,
                              void* d_out, int out_size, void* d_ws, size_t ws_size,
                              hipStream_t stream) {
  const float* x  = (const float*)d_in[0];
  const float* nb = (const float*)d_in[1];
  const float* Wq = (const float*)d_in[2];
  const float* Wk = (const float*)d_in[3];
  const float* Wv = (const float*)d_in[4];
  const float* Wo = (const float*)d_in[5];
  const float* bo = (const float*)d_in[6];
  float* out = (float*)d_out;

  float* ws = (float*)d_ws;
  float* AA = ws;            // [128][512]
  float* CC = ws + 65536;    // [512][128]

  precompute_kernel<<<dim3(256, 2), 256, 0, stream>>>(Wq, Wk, Wv, Wo, AA, CC);
  fused_kernel<<<dim3(NBATCH / BB), NT, 0, stream>>>(x, nb, AA, CC, bo, out);
}